// Round 7
// baseline (472.729 us; speedup 1.0000x reference)
//
#include <hip/hip_runtime.h>
#include <math.h>

typedef float  f32x4  __attribute__((ext_vector_type(4)));
typedef short  s16x8 __attribute__((ext_vector_type(8)));
typedef short  s16x4 __attribute__((ext_vector_type(4)));
typedef unsigned short u16;
typedef unsigned int u32;

// ---------- bf16 helpers ----------
static __device__ __forceinline__ u16 f32_to_bf16_rne(float f) {
    u32 u = __builtin_bit_cast(u32, f);
    u32 r = u + 0x7fffu + ((u >> 16) & 1u);
    return (u16)(r >> 16);
}
static __device__ __forceinline__ u32 pack_bf16_rhu(float a, float b) {
    u32 ua = __builtin_bit_cast(u32, a);
    u32 ub = __builtin_bit_cast(u32, b);
    return ((ua + 0x8000u) >> 16) | ((ub + 0x8000u) & 0xffff0000u);
}

// async global->LDS 16B (lane-contiguous LDS dest ONLY; source is per-lane)
static __device__ __forceinline__ void gl2lds16(const void* g, void* l) {
    __builtin_amdgcn_global_load_lds(
        (const __attribute__((address_space(1))) u32*)g,
        (__attribute__((address_space(3))) u32*)l, 16, 0, 0);
}

// ---------- 1) merged prep: cast x + transpose-cast W_qkv + W_out ----------
// blocks [0,4096): cast x -> xb (8 elems/thread)
// blocks [4096,5632): W_qkv (2048x6144) -> Wqt (6144x2048 bf16), 128x64 tiles
// blocks [5632,6144): W_out (2048x2048) -> Wot, 128x64 tiles
__global__ __launch_bounds__(256) void k_prep(const float* __restrict__ x,
                                              const float* __restrict__ Wq,
                                              const float* __restrict__ Wo,
                                              u16* __restrict__ xb,
                                              u16* __restrict__ Wqt,
                                              u16* __restrict__ Wot) {
    __shared__ float TT[64 * 130];
    const int blk = blockIdx.x;
    const int t = threadIdx.x;
    if (blk < 4096) {
        int i = (blk * 256 + t) * 8;
        float4 a = *reinterpret_cast<const float4*>(x + i);
        float4 b = *reinterpret_cast<const float4*>(x + i + 4);
        s16x8 o;
        o[0] = (short)f32_to_bf16_rne(a.x); o[1] = (short)f32_to_bf16_rne(a.y);
        o[2] = (short)f32_to_bf16_rne(a.z); o[3] = (short)f32_to_bf16_rne(a.w);
        o[4] = (short)f32_to_bf16_rne(b.x); o[5] = (short)f32_to_bf16_rne(b.y);
        o[6] = (short)f32_to_bf16_rne(b.z); o[7] = (short)f32_to_bf16_rne(b.w);
        *reinterpret_cast<s16x8*>(xb + i) = o;
        return;
    }
    const float* in; u16* out; int C, ct, rt;
    if (blk < 5632) {
        int tb = blk - 4096; ct = tb % 96; rt = tb / 96; in = Wq; out = Wqt; C = 6144;
    } else {
        int tb = blk - 5632; ct = tb % 32; rt = tb / 32; in = Wo; out = Wot; C = 2048;
    }
    const int R = 2048;
    const int tr = t >> 4, tc = t & 15;
    float4 v[8];
#pragma unroll
    for (int u = 0; u < 8; ++u) {
        int r = u * 16 + tr;
        v[u] = *reinterpret_cast<const float4*>(in + (size_t)(rt * 128 + r) * C + ct * 64 + tc * 4);
    }
#pragma unroll
    for (int u = 0; u < 8; ++u) {
        int r = u * 16 + tr;
        TT[(tc * 4 + 0) * 130 + r] = v[u].x;
        TT[(tc * 4 + 1) * 130 + r] = v[u].y;
        TT[(tc * 4 + 2) * 130 + r] = v[u].z;
        TT[(tc * 4 + 3) * 130 + r] = v[u].w;
    }
    __syncthreads();
#pragma unroll
    for (int u = 0; u < 4; ++u) {
        int oc = u * 16 + tr;
        int r0 = tc * 8;
        s16x8 o;
#pragma unroll
        for (int e = 0; e < 8; ++e)
            o[e] = (short)f32_to_bf16_rne(TT[oc * 130 + r0 + e]);
        *reinterpret_cast<s16x8*>(out + (size_t)(ct * 64 + oc) * R + rt * 128 + r0) = o;
    }
}

// ---------- 2) 128x384-tile GEMM for QKV (v4 schedule, best measured) ----------
// Grid 16x32 = 512 blocks = exactly 2 occupancy rounds (no tail).
// 8 waves (2M x 4N), per-wave 64x96: acc[4][6] = 96 AGPR.
// Epilogue: Q/K cols (<4096) get RoPE + bf16 -> qkvb; V cols (>=4096) are
// written TRANSPOSED directly into vtg[bh][d][s] (s16x4: 4 consecutive s),
// eliminating the separate V-transpose kernel.
__global__ __launch_bounds__(512, 2) void k_gemm384(const u16* __restrict__ Amat,
                                                    const u16* __restrict__ Bt,
                                                    u16* __restrict__ Cout,
                                                    u16* __restrict__ Vt,
                                                    int M, int N, int K) {
    __shared__ __align__(16) u16 As[2][128 * 64];
    __shared__ __align__(16) u16 Bs[2][384 * 64];
    const int t = threadIdx.x;
    const int lane = t & 63, wave = t >> 6;
    const int m16 = lane & 15, qd = lane >> 4;
    const int wr = wave >> 2, wc = wave & 3;          // 2M x 4N wave grid
    const int srow = lane >> 3;                        // 0..7
    const int sch = (lane & 7) ^ srow;                 // pre-swizzled global k-chunk

    // chunked XCD-aware swizzle for grid 16x32 (8 XCDs, each 4bx x 16by)
    int bx, by;
    if (gridDim.x == 16 && gridDim.y == 32) {
        int orig = blockIdx.y * gridDim.x + blockIdx.x;
        int xcd = orig & 7, loc = orig >> 3;           // loc 0..63
        int cx = xcd & 3, cy = xcd >> 2;
        bx = cx * 4 + (loc & 3);
        by = cy * 16 + (loc >> 2);
    } else {
        bx = blockIdx.x; by = blockIdx.y;
    }
    const size_t m0 = (size_t)by * 128, n0 = (size_t)bx * 384;

    const u16* Ab = Amat + m0 * (size_t)K;
    const u16* Bb = Bt + n0 * (size_t)K;
    const int NT = K >> 6;

    auto stage128 = [&](const u16* gbase, u16* lbase, int k0) {
        int rb0 = wave * 8;
        gl2lds16(gbase + (size_t)(rb0 + srow) * K + k0 + sch * 8, lbase + rb0 * 64);
        int rb1 = rb0 + 64;
        gl2lds16(gbase + (size_t)(rb1 + srow) * K + k0 + sch * 8, lbase + rb1 * 64);
    };

    f32x4 acc[4][6] = {};
    s16x8 af[4][2], bq[6][2];

    // ---- prologue: tile0 (B0,B1,B2,A) -> buf0 ; B0,B1(1) -> buf1 ; vmcnt(4) ----
    stage128(Bb,                   &Bs[0][0],        0);
    stage128(Bb + 128 * (size_t)K, &Bs[0][128 * 64], 0);
    stage128(Bb + 256 * (size_t)K, &Bs[0][256 * 64], 0);
    stage128(Ab,                   &As[0][0],        0);
    if (NT > 1) {
        stage128(Bb,                   &Bs[1][0],        64);
        stage128(Bb + 128 * (size_t)K, &Bs[1][128 * 64], 64);
        asm volatile("s_waitcnt vmcnt(4)" ::: "memory");   // tile0's 8 loads landed
    } else {
        asm volatile("s_waitcnt vmcnt(0)" ::: "memory");
    }
    __builtin_amdgcn_s_barrier();

    for (int kt = 0; kt < NT; ++kt) {
        const int p = kt & 1;

        // ===== region 1: all reads (kh0+kh1); stage B2(t+1),A(t+1)->p^1; MFMA kh0 =====
#pragma unroll
        for (int i = 0; i < 4; ++i) {
            int ra = wr * 64 + i * 16 + m16;
            af[i][0] = *reinterpret_cast<const s16x8*>(&As[p][ra * 64 + ((qd)     ^ (ra & 7)) * 8]);
        }
#pragma unroll
        for (int j = 0; j < 6; ++j) {
            int rb = wc * 96 + j * 16 + m16;
            bq[j][0] = *reinterpret_cast<const s16x8*>(&Bs[p][rb * 64 + ((qd)     ^ (rb & 7)) * 8]);
        }
        if (kt + 1 < NT) stage128(Bb + 256 * (size_t)K, &Bs[p ^ 1][256 * 64], (kt + 1) << 6);
#pragma unroll
        for (int i = 0; i < 4; ++i) {
            int ra = wr * 64 + i * 16 + m16;
            af[i][1] = *reinterpret_cast<const s16x8*>(&As[p][ra * 64 + ((4 + qd) ^ (ra & 7)) * 8]);
        }
#pragma unroll
        for (int j = 0; j < 6; ++j) {
            int rb = wc * 96 + j * 16 + m16;
            bq[j][1] = *reinterpret_cast<const s16x8*>(&Bs[p][rb * 64 + ((4 + qd) ^ (rb & 7)) * 8]);
        }
        if (kt + 1 < NT) stage128(Ab, &As[p ^ 1][0], (kt + 1) << 6);

        __builtin_amdgcn_s_setprio(1);
#pragma unroll
        for (int i = 0; i < 4; ++i)
#pragma unroll
            for (int j = 0; j < 6; ++j)
                acc[i][j] = __builtin_amdgcn_mfma_f32_16x16x32_bf16(af[i][0], bq[j][0], acc[i][j], 0, 0, 0);
        __builtin_amdgcn_s_setprio(0);

        asm volatile("s_waitcnt lgkmcnt(0)" ::: "memory");   // ~free; WAR guard
        __builtin_amdgcn_s_barrier();                        // B_mid: p reads done

        // ===== region 2: stage B0,B1(t+2)->p; MFMA kh1; counted vmcnt; B_end =====
        if (kt + 2 < NT) {
            stage128(Bb,                   &Bs[p][0],        (kt + 2) << 6);
            stage128(Bb + 128 * (size_t)K, &Bs[p][128 * 64], (kt + 2) << 6);
        }
        __builtin_amdgcn_s_setprio(1);
#pragma unroll
        for (int i = 0; i < 4; ++i)
#pragma unroll
            for (int j = 0; j < 6; ++j)
                acc[i][j] = __builtin_amdgcn_mfma_f32_16x16x32_bf16(af[i][1], bq[j][1], acc[i][j], 0, 0, 0);
        __builtin_amdgcn_s_setprio(0);
        if (kt + 2 < NT) {
            asm volatile("s_waitcnt vmcnt(4)" ::: "memory"); // retires tile t+1 exactly
        } else {
            asm volatile("s_waitcnt vmcnt(0)" ::: "memory");
        }
        __builtin_amdgcn_s_barrier();                        // B_end
    }

    // ---- epilogue: Q/K -> RoPE + qkvb ; V -> transposed vtg[bh][d][s] ----
    {
        float invf[6];
#pragma unroll
        for (int j = 0; j < 6; ++j) {
            int pi = ((int)(n0 + wc * 96 + j * 16 + m16) & 127) >> 1;
            invf[j] = __expf(-0.14391156831f * (float)pi);
        }
#pragma unroll
        for (int i = 0; i < 4; ++i)
#pragma unroll
            for (int j = 0; j < 6; ++j) {
                size_t colbase = n0 + wc * 96 + j * 16;
                if (colbase < 4096) {
#pragma unroll
                    for (int r = 0; r < 4; ++r) {
                        float v = acc[i][j][r];
                        float pv = __shfl_xor(v, 1);
                        size_t row = m0 + wr * 64 + i * 16 + qd * 4 + r;
                        float f = (float)(int)(row & 2047) * invf[j];
                        float sn, cs;
                        __sincosf(f, &sn, &cs);
                        float res = (m16 & 1) ? fmaf(pv, sn, v * cs) : fmaf(v, cs, -pv * sn);
                        Cout[row * N + colbase + m16] = f32_to_bf16_rne(res);
                    }
                } else {
                    // V columns: write transposed to vtg. lane column:
                    int vcol = (int)colbase - 4096 + m16;       // 0..2047
                    int h = vcol >> 7, d = vcol & 127;
                    size_t row0 = m0 + wr * 64 + i * 16 + qd * 4;   // 4 consecutive s
                    int b = (int)(row0 >> 11);
                    int s = (int)(row0 & 2047);
                    s16x4 o;
#pragma unroll
                    for (int r = 0; r < 4; ++r)
                        o[r] = (short)f32_to_bf16_rne(acc[i][j][r]);
                    *reinterpret_cast<s16x4*>(
                        Vt + ((size_t)(b * 16 + h)) * 262144 + (size_t)d * 2048 + s) = o;
                }
            }
    }
}

// ---------- 3) out-projection GEMM, 128x256 tile, v4 schedule ----------
__global__ __launch_bounds__(512, 2) void k_gemmo(const u16* __restrict__ Amat,
                                                  const u16* __restrict__ Bt,
                                                  float* __restrict__ Cout,
                                                  int M, int N, int K) {
    __shared__ __align__(16) u16 As[2][128 * 64];
    __shared__ __align__(16) u16 Bs[2][256 * 64];
    const int t = threadIdx.x;
    const int lane = t & 63, wave = t >> 6;
    const int m16 = lane & 15, qd = lane >> 4;
    const int wr = wave >> 2, wc = wave & 3;
    const int srow = lane >> 3;
    const int sch = (lane & 7) ^ srow;

    int bx, by;
    if (gridDim.x == 8 && gridDim.y == 32) {
        int orig = blockIdx.y * gridDim.x + blockIdx.x;
        int xcd = orig & 7, loc = orig >> 3;
        int cx = xcd & 1, cy = xcd >> 1;
        bx = cx * 4 + (loc & 3);
        by = cy * 8 + (loc >> 2);
    } else {
        bx = blockIdx.x; by = blockIdx.y;
    }
    const size_t m0 = (size_t)by * 128, n0 = (size_t)bx * 256;

    const u16* Ab = Amat + m0 * (size_t)K;
    const u16* Bb = Bt + n0 * (size_t)K;
    const int NT = K >> 6;

    auto stage128 = [&](const u16* gbase, u16* lbase, int k0) {
        int rb0 = wave * 8;
        gl2lds16(gbase + (size_t)(rb0 + srow) * K + k0 + sch * 8, lbase + rb0 * 64);
        int rb1 = rb0 + 64;
        gl2lds16(gbase + (size_t)(rb1 + srow) * K + k0 + sch * 8, lbase + rb1 * 64);
    };

    f32x4 acc[4][4] = {};
    s16x8 af[4][2], bq[4][2];

    stage128(Ab,                   &As[0][0],        0);
    stage128(Bb,                   &Bs[0][0],        0);
    stage128(Bb + 128 * (size_t)K, &Bs[0][128 * 64], 0);
    if (NT > 1) {
        stage128(Ab,               &As[1][0],        64);
        stage128(Bb,               &Bs[1][0],        64);
        asm volatile("s_waitcnt vmcnt(4)" ::: "memory");
    } else {
        asm volatile("s_waitcnt vmcnt(0)" ::: "memory");
    }
    __builtin_amdgcn_s_barrier();

    for (int kt = 0; kt < NT; ++kt) {
        const int p = kt & 1;

#pragma unroll
        for (int i = 0; i < 4; ++i) {
            int ra = wr * 64 + i * 16 + m16;
            af[i][0] = *reinterpret_cast<const s16x8*>(&As[p][ra * 64 + ((qd)     ^ (ra & 7)) * 8]);
        }
#pragma unroll
        for (int j = 0; j < 4; ++j) {
            int rb = wc * 64 + j * 16 + m16;
            bq[j][0] = *reinterpret_cast<const s16x8*>(&Bs[p][rb * 64 + ((qd)     ^ (rb & 7)) * 8]);
        }
        if (kt + 1 < NT) stage128(Bb + 128 * (size_t)K, &Bs[p ^ 1][128 * 64], (kt + 1) << 6);
#pragma unroll
        for (int i = 0; i < 4; ++i) {
            int ra = wr * 64 + i * 16 + m16;
            af[i][1] = *reinterpret_cast<const s16x8*>(&As[p][ra * 64 + ((4 + qd) ^ (ra & 7)) * 8]);
        }
#pragma unroll
        for (int j = 0; j < 4; ++j) {
            int rb = wc * 64 + j * 16 + m16;
            bq[j][1] = *reinterpret_cast<const s16x8*>(&Bs[p][rb * 64 + ((4 + qd) ^ (rb & 7)) * 8]);
        }

        __builtin_amdgcn_s_setprio(1);
#pragma unroll
        for (int i = 0; i < 4; ++i)
#pragma unroll
            for (int j = 0; j < 4; ++j)
                acc[i][j] = __builtin_amdgcn_mfma_f32_16x16x32_bf16(af[i][0], bq[j][0], acc[i][j], 0, 0, 0);
        __builtin_amdgcn_s_setprio(0);

        asm volatile("s_waitcnt lgkmcnt(0)" ::: "memory");
        __builtin_amdgcn_s_barrier();

        if (kt + 2 < NT) {
            stage128(Ab, &As[p][0], (kt + 2) << 6);
            stage128(Bb, &Bs[p][0], (kt + 2) << 6);
        }
        __builtin_amdgcn_s_setprio(1);
#pragma unroll
        for (int i = 0; i < 4; ++i)
#pragma unroll
            for (int j = 0; j < 4; ++j)
                acc[i][j] = __builtin_amdgcn_mfma_f32_16x16x32_bf16(af[i][1], bq[j][1], acc[i][j], 0, 0, 0);
        __builtin_amdgcn_s_setprio(0);
        if (kt + 2 < NT) {
            asm volatile("s_waitcnt vmcnt(4)" ::: "memory");
        } else {
            asm volatile("s_waitcnt vmcnt(0)" ::: "memory");
        }
        __builtin_amdgcn_s_barrier();
    }

#pragma unroll
    for (int i = 0; i < 4; ++i)
#pragma unroll
        for (int j = 0; j < 4; ++j)
#pragma unroll
            for (int r = 0; r < 4; ++r) {
                size_t row = m0 + wr * 64 + i * 16 + qd * 4 + r;
                size_t col = n0 + wc * 64 + j * 16 + m16;
                Cout[row * N + col] = acc[i][j][r];
            }
}

// ---------- 4) flash attention (+T14 prefetch-under-PV, +T5 setprio) ----------
__global__ __launch_bounds__(512, 4) void k_flash(const u16* __restrict__ qkv,
                                                  const u16* __restrict__ vt,
                                                  u16* __restrict__ out) {
    __shared__ __align__(16) u16 KS[128 * 136];
    __shared__ __align__(16) u16 VS[128 * 136];
    const int t = threadIdx.x, lane = t & 63, wave = t >> 6;
    const int m16 = lane & 15, qd = lane >> 4;
    const int bh = blockIdx.y, b = bh >> 4, h = bh & 15;
    const int q0 = blockIdx.x * 128;
    const u16* Qg = qkv + (size_t)b * 2048 * 6144 + (size_t)h * 128;
    const u16* Kg = Qg + 2048;
    const u16* Vtg = vt + (size_t)bh * 128 * 2048;
    const float C2 = 0.12751743f;   // (1/sqrt(128)) * log2(e)

    int srow[4], scol[4], pi0[4];
#pragma unroll
    for (int ci = 0; ci < 4; ++ci) {
        int idx = ci * 512 + t;
        int row = idx >> 4, c = idx & 15;
        srow[ci] = row;
        scol[ci] = c * 8;
        pi0[ci] = 32 * (c >> 2) + 16 * (c & 1) + 4 * ((c >> 1) & 1);
    }

    s16x8 qf[4];
#pragma unroll
    for (int kc = 0; kc < 4; ++kc)
        qf[kc] = *reinterpret_cast<const s16x8*>(
            Qg + (size_t)(q0 + wave * 16 + m16) * 6144 + kc * 32 + qd * 8);

    f32x4 accO[8] = {};
    float mrow = -1e30f, lrow = 0.f;

    // prologue: load tile 0 into registers
    s16x8 kreg[4], vreg[4];
#pragma unroll
    for (int ci = 0; ci < 4; ++ci) {
        kreg[ci] = *reinterpret_cast<const s16x8*>(Kg + (size_t)srow[ci] * 6144 + scol[ci]);
        vreg[ci] = *reinterpret_cast<const s16x8*>(Vtg + (size_t)srow[ci] * 2048 + scol[ci]);
    }

    for (int kt = 0; kt < 16; ++kt) {
        __syncthreads();      // WAR: everyone done reading KS/VS from kt-1
#pragma unroll
        for (int ci = 0; ci < 4; ++ci) {
            *reinterpret_cast<s16x8*>(&KS[srow[ci] * 136 + scol[ci]]) = kreg[ci];
            s16x4 lo = __builtin_shufflevector(vreg[ci], vreg[ci], 0, 1, 2, 3);
            s16x4 hi = __builtin_shufflevector(vreg[ci], vreg[ci], 4, 5, 6, 7);
            *reinterpret_cast<s16x4*>(&VS[srow[ci] * 136 + pi0[ci]]) = lo;
            *reinterpret_cast<s16x4*>(&VS[srow[ci] * 136 + pi0[ci] + 8]) = hi;
        }
        __syncthreads();

        f32x4 accS[8] = {};
        __builtin_amdgcn_s_setprio(1);
#pragma unroll
        for (int kc = 0; kc < 4; ++kc)
#pragma unroll
            for (int nj = 0; nj < 8; ++nj) {
                s16x8 kf = *reinterpret_cast<const s16x8*>(
                    &KS[(nj * 16 + m16) * 136 + (kc * 4 + qd) * 8]);
                accS[nj] = __builtin_amdgcn_mfma_f32_16x16x32_bf16(kf, qf[kc], accS[nj], 0, 0, 0);
            }
        __builtin_amdgcn_s_setprio(0);

        float mx = accS[0][0];
#pragma unroll
        for (int nj = 0; nj < 8; ++nj)
#pragma unroll
            for (int r = 0; r < 4; ++r) mx = fmaxf(mx, accS[nj][r]);
        mx *= C2;
        mx = fmaxf(mx, __shfl_xor(mx, 16));
        mx = fmaxf(mx, __shfl_xor(mx, 32));
        float mn = fmaxf(mrow, mx);
        float alpha = __builtin_amdgcn_exp2f(mrow - mn);
        mrow = mn;
        float ls = 0.f;
        s16x4 pk[8];
#pragma unroll
        for (int nj = 0; nj < 8; ++nj) {
            float p0 = __builtin_amdgcn_exp2f(fmaf(accS[nj][0], C2, -mn));
            float p1 = __builtin_amdgcn_exp2f(fmaf(accS[nj][1], C2, -mn));
            float p2 = __builtin_amdgcn_exp2f(fmaf(accS[nj][2], C2, -mn));
            float p3 = __builtin_amdgcn_exp2f(fmaf(accS[nj][3], C2, -mn));
            ls += (p0 + p1) + (p2 + p3);
            u32 lo = pack_bf16_rhu(p0, p1);
            u32 hi = pack_bf16_rhu(p2, p3);
            uint2 pr = make_uint2(lo, hi);
            pk[nj] = __builtin_bit_cast(s16x4, pr);
        }

        // T14: issue next-tile loads here — accS is dead (regs free), the
        // ~L2 latency hides under the PV MFMA cluster below.
        if (kt + 1 < 16) {
            const int sn = (kt + 1) * 128;
#pragma unroll
            for (int ci = 0; ci < 4; ++ci) {
                kreg[ci] = *reinterpret_cast<const s16x8*>(
                    Kg + (size_t)(sn + srow[ci]) * 6144 + scol[ci]);
                vreg[ci] = *reinterpret_cast<const s16x8*>(
                    Vtg + (size_t)srow[ci] * 2048 + sn + scol[ci]);
            }
        }

        ls += __shfl_xor(ls, 16);
        ls += __shfl_xor(ls, 32);
        lrow = lrow * alpha + ls;
        float aO[4];
#pragma unroll
        for (int r = 0; r < 4; ++r) aO[r] = __shfl(alpha, qd * 4 + r);
#pragma unroll
        for (int dj = 0; dj < 8; ++dj)
#pragma unroll
            for (int r = 0; r < 4; ++r) accO[dj][r] *= aO[r];

        __builtin_amdgcn_s_setprio(1);
#pragma unroll
        for (int kb = 0; kb < 4; ++kb) {
            s16x8 af = __builtin_shufflevector(pk[2 * kb], pk[2 * kb + 1],
                                               0, 1, 2, 3, 4, 5, 6, 7);
#pragma unroll
            for (int dj = 0; dj < 8; ++dj) {
                s16x8 vf = *reinterpret_cast<const s16x8*>(
                    &VS[(dj * 16 + m16) * 136 + kb * 32 + qd * 8]);
                accO[dj] = __builtin_amdgcn_mfma_f32_16x16x32_bf16(af, vf, accO[dj], 0, 0, 0);
            }
        }
        __builtin_amdgcn_s_setprio(0);
    }
    float invl = 1.0f / lrow;
    float iv[4];
#pragma unroll
    for (int r = 0; r < 4; ++r) iv[r] = __shfl(invl, qd * 4 + r);
#pragma unroll
    for (int r = 0; r < 4; ++r) {
        size_t row = (size_t)b * 2048 + q0 + wave * 16 + qd * 4 + r;
#pragma unroll
        for (int dj = 0; dj < 8; ++dj)
            out[row * 2048 + h * 128 + dj * 16 + m16] =
                f32_to_bf16_rne(accO[dj][r] * iv[r]);
    }
}

// ---------- launch: 4 dispatches (was 7) ----------
extern "C" void kernel_launch(void* const* d_in, const int* in_sizes, int n_in,
                              void* d_out, int out_size, void* d_ws, size_t ws_size,
                              hipStream_t stream) {
    const float* x     = (const float*)d_in[0];
    const float* W_qkv = (const float*)d_in[1];
    const float* W_out = (const float*)d_in[2];
    float* out = (float*)d_out;

    char* ws = (char*)d_ws;
    u16* xb   = (u16*)(ws);
    u16* Wqt  = (u16*)(ws + (16u << 20));
    u16* Wot  = (u16*)(ws + (40u << 20));
    u16* qkvb = (u16*)(ws + (48u << 20));
    u16* attn = (u16*)(ws + (96u << 20));
    u16* vtg  = (u16*)(ws + (112u << 20));

    k_prep<<<6144, 256, 0, stream>>>(x, W_qkv, W_out, xb, Wqt, Wot);
    k_gemm384<<<dim3(16, 32), 512, 0, stream>>>(xb, Wqt, qkvb, vtg, 4096, 6144, 2048);
    k_flash<<<dim3(16, 32), 512, 0, stream>>>(qkvb, vtg, attn);
    k_gemmo<<<dim3(8, 32), 512, 0, stream>>>(attn, Wot, out, 4096, 2048, 2048);
}

// Round 9
// 390.527 us; speedup vs baseline: 1.2105x; 1.2105x over previous
//
#include <hip/hip_runtime.h>
#include <math.h>

typedef float  f32x4  __attribute__((ext_vector_type(4)));
typedef short  s16x8 __attribute__((ext_vector_type(8)));
typedef short  s16x4 __attribute__((ext_vector_type(4)));
typedef unsigned short u16;
typedef unsigned int u32;

// ---------- bf16 helpers ----------
static __device__ __forceinline__ u16 f32_to_bf16_rne(float f) {
    u32 u = __builtin_bit_cast(u32, f);
    u32 r = u + 0x7fffu + ((u >> 16) & 1u);
    return (u16)(r >> 16);
}
static __device__ __forceinline__ u32 pack_bf16_rhu(float a, float b) {
    u32 ua = __builtin_bit_cast(u32, a);
    u32 ub = __builtin_bit_cast(u32, b);
    return ((ua + 0x8000u) >> 16) | ((ub + 0x8000u) & 0xffff0000u);
}

// async global->LDS 16B (lane-contiguous LDS dest ONLY; source is per-lane)
static __device__ __forceinline__ void gl2lds16(const void* g, void* l) {
    __builtin_amdgcn_global_load_lds(
        (const __attribute__((address_space(1))) u32*)g,
        (__attribute__((address_space(3))) u32*)l, 16, 0, 0);
}

// ---------- 1) merged prep: cast x + transpose-cast W_qkv + W_out ----------
__global__ __launch_bounds__(256) void k_prep(const float* __restrict__ x,
                                              const float* __restrict__ Wq,
                                              const float* __restrict__ Wo,
                                              u16* __restrict__ xb,
                                              u16* __restrict__ Wqt,
                                              u16* __restrict__ Wot) {
    __shared__ float TT[64 * 130];
    const int blk = blockIdx.x;
    const int t = threadIdx.x;
    if (blk < 4096) {
        int i = (blk * 256 + t) * 8;
        float4 a = *reinterpret_cast<const float4*>(x + i);
        float4 b = *reinterpret_cast<const float4*>(x + i + 4);
        s16x8 o;
        o[0] = (short)f32_to_bf16_rne(a.x); o[1] = (short)f32_to_bf16_rne(a.y);
        o[2] = (short)f32_to_bf16_rne(a.z); o[3] = (short)f32_to_bf16_rne(a.w);
        o[4] = (short)f32_to_bf16_rne(b.x); o[5] = (short)f32_to_bf16_rne(b.y);
        o[6] = (short)f32_to_bf16_rne(b.z); o[7] = (short)f32_to_bf16_rne(b.w);
        *reinterpret_cast<s16x8*>(xb + i) = o;
        return;
    }
    const float* in; u16* out; int C, ct, rt;
    if (blk < 5632) {
        int tb = blk - 4096; ct = tb % 96; rt = tb / 96; in = Wq; out = Wqt; C = 6144;
    } else {
        int tb = blk - 5632; ct = tb % 32; rt = tb / 32; in = Wo; out = Wot; C = 2048;
    }
    const int R = 2048;
    const int tr = t >> 4, tc = t & 15;
    float4 v[8];
#pragma unroll
    for (int u = 0; u < 8; ++u) {
        int r = u * 16 + tr;
        v[u] = *reinterpret_cast<const float4*>(in + (size_t)(rt * 128 + r) * C + ct * 64 + tc * 4);
    }
#pragma unroll
    for (int u = 0; u < 8; ++u) {
        int r = u * 16 + tr;
        TT[(tc * 4 + 0) * 130 + r] = v[u].x;
        TT[(tc * 4 + 1) * 130 + r] = v[u].y;
        TT[(tc * 4 + 2) * 130 + r] = v[u].z;
        TT[(tc * 4 + 3) * 130 + r] = v[u].w;
    }
    __syncthreads();
#pragma unroll
    for (int u = 0; u < 4; ++u) {
        int oc = u * 16 + tr;
        int r0 = tc * 8;
        s16x8 o;
#pragma unroll
        for (int e = 0; e < 8; ++e)
            o[e] = (short)f32_to_bf16_rne(TT[oc * 130 + r0 + e]);
        *reinterpret_cast<s16x8*>(out + (size_t)(ct * 64 + oc) * R + rt * 128 + r0) = o;
    }
}

// ---------- 2) 128x384-tile GEMM for QKV (v4 schedule) ----------
// Epilogue: Q/K cols (<4096) get RoPE + bf16 -> qkvb; V cols (>=4096) are
// written TRANSPOSED directly into vtg[bh][d][s] (s16x4: 4 consecutive s).
__global__ __launch_bounds__(512, 2) void k_gemm384(const u16* __restrict__ Amat,
                                                    const u16* __restrict__ Bt,
                                                    u16* __restrict__ Cout,
                                                    u16* __restrict__ Vt,
                                                    int M, int N, int K) {
    __shared__ __align__(16) u16 As[2][128 * 64];
    __shared__ __align__(16) u16 Bs[2][384 * 64];
    const int t = threadIdx.x;
    const int lane = t & 63, wave = t >> 6;
    const int m16 = lane & 15, qd = lane >> 4;
    const int wr = wave >> 2, wc = wave & 3;
    const int srow = lane >> 3;
    const int sch = (lane & 7) ^ srow;

    int bx, by;
    if (gridDim.x == 16 && gridDim.y == 32) {
        int orig = blockIdx.y * gridDim.x + blockIdx.x;
        int xcd = orig & 7, loc = orig >> 3;
        int cx = xcd & 3, cy = xcd >> 2;
        bx = cx * 4 + (loc & 3);
        by = cy * 16 + (loc >> 2);
    } else {
        bx = blockIdx.x; by = blockIdx.y;
    }
    const size_t m0 = (size_t)by * 128, n0 = (size_t)bx * 384;

    const u16* Ab = Amat + m0 * (size_t)K;
    const u16* Bb = Bt + n0 * (size_t)K;
    const int NT = K >> 6;

    auto stage128 = [&](const u16* gbase, u16* lbase, int k0) {
        int rb0 = wave * 8;
        gl2lds16(gbase + (size_t)(rb0 + srow) * K + k0 + sch * 8, lbase + rb0 * 64);
        int rb1 = rb0 + 64;
        gl2lds16(gbase + (size_t)(rb1 + srow) * K + k0 + sch * 8, lbase + rb1 * 64);
    };

    f32x4 acc[4][6] = {};
    s16x8 af[4][2], bq[6][2];

    stage128(Bb,                   &Bs[0][0],        0);
    stage128(Bb + 128 * (size_t)K, &Bs[0][128 * 64], 0);
    stage128(Bb + 256 * (size_t)K, &Bs[0][256 * 64], 0);
    stage128(Ab,                   &As[0][0],        0);
    if (NT > 1) {
        stage128(Bb,                   &Bs[1][0],        64);
        stage128(Bb + 128 * (size_t)K, &Bs[1][128 * 64], 64);
        asm volatile("s_waitcnt vmcnt(4)" ::: "memory");
    } else {
        asm volatile("s_waitcnt vmcnt(0)" ::: "memory");
    }
    __builtin_amdgcn_s_barrier();

    for (int kt = 0; kt < NT; ++kt) {
        const int p = kt & 1;

#pragma unroll
        for (int i = 0; i < 4; ++i) {
            int ra = wr * 64 + i * 16 + m16;
            af[i][0] = *reinterpret_cast<const s16x8*>(&As[p][ra * 64 + ((qd)     ^ (ra & 7)) * 8]);
        }
#pragma unroll
        for (int j = 0; j < 6; ++j) {
            int rb = wc * 96 + j * 16 + m16;
            bq[j][0] = *reinterpret_cast<const s16x8*>(&Bs[p][rb * 64 + ((qd)     ^ (rb & 7)) * 8]);
        }
        if (kt + 1 < NT) stage128(Bb + 256 * (size_t)K, &Bs[p ^ 1][256 * 64], (kt + 1) << 6);
#pragma unroll
        for (int i = 0; i < 4; ++i) {
            int ra = wr * 64 + i * 16 + m16;
            af[i][1] = *reinterpret_cast<const s16x8*>(&As[p][ra * 64 + ((4 + qd) ^ (ra & 7)) * 8]);
        }
#pragma unroll
        for (int j = 0; j < 6; ++j) {
            int rb = wc * 96 + j * 16 + m16;
            bq[j][1] = *reinterpret_cast<const s16x8*>(&Bs[p][rb * 64 + ((4 + qd) ^ (rb & 7)) * 8]);
        }
        if (kt + 1 < NT) stage128(Ab, &As[p ^ 1][0], (kt + 1) << 6);

        __builtin_amdgcn_s_setprio(1);
#pragma unroll
        for (int i = 0; i < 4; ++i)
#pragma unroll
            for (int j = 0; j < 6; ++j)
                acc[i][j] = __builtin_amdgcn_mfma_f32_16x16x32_bf16(af[i][0], bq[j][0], acc[i][j], 0, 0, 0);
        __builtin_amdgcn_s_setprio(0);

        asm volatile("s_waitcnt lgkmcnt(0)" ::: "memory");
        __builtin_amdgcn_s_barrier();

        if (kt + 2 < NT) {
            stage128(Bb,                   &Bs[p][0],        (kt + 2) << 6);
            stage128(Bb + 128 * (size_t)K, &Bs[p][128 * 64], (kt + 2) << 6);
        }
        __builtin_amdgcn_s_setprio(1);
#pragma unroll
        for (int i = 0; i < 4; ++i)
#pragma unroll
            for (int j = 0; j < 6; ++j)
                acc[i][j] = __builtin_amdgcn_mfma_f32_16x16x32_bf16(af[i][1], bq[j][1], acc[i][j], 0, 0, 0);
        __builtin_amdgcn_s_setprio(0);
        if (kt + 2 < NT) {
            asm volatile("s_waitcnt vmcnt(4)" ::: "memory");
        } else {
            asm volatile("s_waitcnt vmcnt(0)" ::: "memory");
        }
        __builtin_amdgcn_s_barrier();
    }

    // ---- epilogue: Q/K -> RoPE + qkvb ; V -> transposed vtg[bh][d][s] ----
    {
        float invf[6];
#pragma unroll
        for (int j = 0; j < 6; ++j) {
            int pi = ((int)(n0 + wc * 96 + j * 16 + m16) & 127) >> 1;
            invf[j] = __expf(-0.14391156831f * (float)pi);
        }
#pragma unroll
        for (int i = 0; i < 4; ++i)
#pragma unroll
            for (int j = 0; j < 6; ++j) {
                size_t colbase = n0 + wc * 96 + j * 16;
                if (colbase < 4096) {
#pragma unroll
                    for (int r = 0; r < 4; ++r) {
                        float v = acc[i][j][r];
                        float pv = __shfl_xor(v, 1);
                        size_t row = m0 + wr * 64 + i * 16 + qd * 4 + r;
                        float f = (float)(int)(row & 2047) * invf[j];
                        float sn, cs;
                        __sincosf(f, &sn, &cs);
                        float res = (m16 & 1) ? fmaf(pv, sn, v * cs) : fmaf(v, cs, -pv * sn);
                        Cout[row * N + colbase + m16] = f32_to_bf16_rne(res);
                    }
                } else {
                    int vcol = (int)colbase - 4096 + m16;       // 0..2047
                    int h = vcol >> 7, d = vcol & 127;
                    size_t row0 = m0 + wr * 64 + i * 16 + qd * 4;
                    int b = (int)(row0 >> 11);
                    int s = (int)(row0 & 2047);
                    s16x4 o;
#pragma unroll
                    for (int r = 0; r < 4; ++r)
                        o[r] = (short)f32_to_bf16_rne(acc[i][j][r]);
                    *reinterpret_cast<s16x4*>(
                        Vt + ((size_t)(b * 16 + h)) * 262144 + (size_t)d * 2048 + s) = o;
                }
            }
    }
}

// ---------- 3) out-projection GEMM, 128x256 tile, v4 schedule ----------
__global__ __launch_bounds__(512, 2) void k_gemmo(const u16* __restrict__ Amat,
                                                  const u16* __restrict__ Bt,
                                                  float* __restrict__ Cout,
                                                  int M, int N, int K) {
    __shared__ __align__(16) u16 As[2][128 * 64];
    __shared__ __align__(16) u16 Bs[2][256 * 64];
    const int t = threadIdx.x;
    const int lane = t & 63, wave = t >> 6;
    const int m16 = lane & 15, qd = lane >> 4;
    const int wr = wave >> 2, wc = wave & 3;
    const int srow = lane >> 3;
    const int sch = (lane & 7) ^ srow;

    int bx, by;
    if (gridDim.x == 8 && gridDim.y == 32) {
        int orig = blockIdx.y * gridDim.x + blockIdx.x;
        int xcd = orig & 7, loc = orig >> 3;
        int cx = xcd & 1, cy = xcd >> 1;
        bx = cx * 4 + (loc & 3);
        by = cy * 8 + (loc >> 2);
    } else {
        bx = blockIdx.x; by = blockIdx.y;
    }
    const size_t m0 = (size_t)by * 128, n0 = (size_t)bx * 256;

    const u16* Ab = Amat + m0 * (size_t)K;
    const u16* Bb = Bt + n0 * (size_t)K;
    const int NT = K >> 6;

    auto stage128 = [&](const u16* gbase, u16* lbase, int k0) {
        int rb0 = wave * 8;
        gl2lds16(gbase + (size_t)(rb0 + srow) * K + k0 + sch * 8, lbase + rb0 * 64);
        int rb1 = rb0 + 64;
        gl2lds16(gbase + (size_t)(rb1 + srow) * K + k0 + sch * 8, lbase + rb1 * 64);
    };

    f32x4 acc[4][4] = {};
    s16x8 af[4][2], bq[4][2];

    stage128(Ab,                   &As[0][0],        0);
    stage128(Bb,                   &Bs[0][0],        0);
    stage128(Bb + 128 * (size_t)K, &Bs[0][128 * 64], 0);
    if (NT > 1) {
        stage128(Ab,               &As[1][0],        64);
        stage128(Bb,               &Bs[1][0],        64);
        asm volatile("s_waitcnt vmcnt(4)" ::: "memory");
    } else {
        asm volatile("s_waitcnt vmcnt(0)" ::: "memory");
    }
    __builtin_amdgcn_s_barrier();

    for (int kt = 0; kt < NT; ++kt) {
        const int p = kt & 1;

#pragma unroll
        for (int i = 0; i < 4; ++i) {
            int ra = wr * 64 + i * 16 + m16;
            af[i][0] = *reinterpret_cast<const s16x8*>(&As[p][ra * 64 + ((qd)     ^ (ra & 7)) * 8]);
        }
#pragma unroll
        for (int j = 0; j < 4; ++j) {
            int rb = wc * 64 + j * 16 + m16;
            bq[j][0] = *reinterpret_cast<const s16x8*>(&Bs[p][rb * 64 + ((qd)     ^ (rb & 7)) * 8]);
        }
        if (kt + 1 < NT) stage128(Bb + 128 * (size_t)K, &Bs[p ^ 1][128 * 64], (kt + 1) << 6);
#pragma unroll
        for (int i = 0; i < 4; ++i) {
            int ra = wr * 64 + i * 16 + m16;
            af[i][1] = *reinterpret_cast<const s16x8*>(&As[p][ra * 64 + ((4 + qd) ^ (ra & 7)) * 8]);
        }
#pragma unroll
        for (int j = 0; j < 4; ++j) {
            int rb = wc * 64 + j * 16 + m16;
            bq[j][1] = *reinterpret_cast<const s16x8*>(&Bs[p][rb * 64 + ((4 + qd) ^ (rb & 7)) * 8]);
        }

        __builtin_amdgcn_s_setprio(1);
#pragma unroll
        for (int i = 0; i < 4; ++i)
#pragma unroll
            for (int j = 0; j < 4; ++j)
                acc[i][j] = __builtin_amdgcn_mfma_f32_16x16x32_bf16(af[i][0], bq[j][0], acc[i][j], 0, 0, 0);
        __builtin_amdgcn_s_setprio(0);

        asm volatile("s_waitcnt lgkmcnt(0)" ::: "memory");
        __builtin_amdgcn_s_barrier();

        if (kt + 2 < NT) {
            stage128(Ab, &As[p][0], (kt + 2) << 6);
            stage128(Bb, &Bs[p][0], (kt + 2) << 6);
        }
        __builtin_amdgcn_s_setprio(1);
#pragma unroll
        for (int i = 0; i < 4; ++i)
#pragma unroll
            for (int j = 0; j < 4; ++j)
                acc[i][j] = __builtin_amdgcn_mfma_f32_16x16x32_bf16(af[i][1], bq[j][1], acc[i][j], 0, 0, 0);
        __builtin_amdgcn_s_setprio(0);
        if (kt + 2 < NT) {
            asm volatile("s_waitcnt vmcnt(4)" ::: "memory");
        } else {
            asm volatile("s_waitcnt vmcnt(0)" ::: "memory");
        }
        __builtin_amdgcn_s_barrier();
    }

#pragma unroll
    for (int i = 0; i < 4; ++i)
#pragma unroll
        for (int j = 0; j < 4; ++j)
#pragma unroll
            for (int r = 0; r < 4; ++r) {
                size_t row = m0 + wr * 64 + i * 16 + qd * 4 + r;
                size_t col = n0 + wc * 64 + j * 16 + m16;
                Cout[row * N + col] = acc[i][j][r];
            }
}

// ---------- 4) flash attention — EXACT R6 form (protected win; short K/V
// register live-range: load at loop top, park in LDS immediately) ----------
__global__ __launch_bounds__(512, 4) void k_flash(const u16* __restrict__ qkv,
                                                  const u16* __restrict__ vt,
                                                  u16* __restrict__ out) {
    __shared__ __align__(16) u16 KS[128 * 136];
    __shared__ __align__(16) u16 VS[128 * 136];
    const int t = threadIdx.x, lane = t & 63, wave = t >> 6;
    const int m16 = lane & 15, qd = lane >> 4;
    const int bh = blockIdx.y, b = bh >> 4, h = bh & 15;
    const int q0 = blockIdx.x * 128;
    const u16* Qg = qkv + (size_t)b * 2048 * 6144 + (size_t)h * 128;
    const u16* Kg = Qg + 2048;
    const u16* Vtg = vt + (size_t)bh * 128 * 2048;
    const float C2 = 0.12751743f;

    int srow[4], scol[4], pi0[4];
#pragma unroll
    for (int ci = 0; ci < 4; ++ci) {
        int idx = ci * 512 + t;
        int row = idx >> 4, c = idx & 15;
        srow[ci] = row;
        scol[ci] = c * 8;
        pi0[ci] = 32 * (c >> 2) + 16 * (c & 1) + 4 * ((c >> 1) & 1);
    }

    s16x8 qf[4];
#pragma unroll
    for (int kc = 0; kc < 4; ++kc)
        qf[kc] = *reinterpret_cast<const s16x8*>(
            Qg + (size_t)(q0 + wave * 16 + m16) * 6144 + kc * 32 + qd * 8);

    f32x4 accO[8] = {};
    float mrow = -1e30f, lrow = 0.f;

    for (int kt = 0; kt < 16; ++kt) {
        const int s0 = kt * 128;
        s16x8 kreg[4], vreg[4];
#pragma unroll
        for (int ci = 0; ci < 4; ++ci) {
            kreg[ci] = *reinterpret_cast<const s16x8*>(
                Kg + (size_t)(s0 + srow[ci]) * 6144 + scol[ci]);
            vreg[ci] = *reinterpret_cast<const s16x8*>(
                Vtg + (size_t)srow[ci] * 2048 + s0 + scol[ci]);
        }
        __syncthreads();
#pragma unroll
        for (int ci = 0; ci < 4; ++ci) {
            *reinterpret_cast<s16x8*>(&KS[srow[ci] * 136 + scol[ci]]) = kreg[ci];
            s16x4 lo = __builtin_shufflevector(vreg[ci], vreg[ci], 0, 1, 2, 3);
            s16x4 hi = __builtin_shufflevector(vreg[ci], vreg[ci], 4, 5, 6, 7);
            *reinterpret_cast<s16x4*>(&VS[srow[ci] * 136 + pi0[ci]]) = lo;
            *reinterpret_cast<s16x4*>(&VS[srow[ci] * 136 + pi0[ci] + 8]) = hi;
        }
        __syncthreads();

        f32x4 accS[8] = {};
#pragma unroll
        for (int kc = 0; kc < 4; ++kc)
#pragma unroll
            for (int nj = 0; nj < 8; ++nj) {
                s16x8 kf = *reinterpret_cast<const s16x8*>(
                    &KS[(nj * 16 + m16) * 136 + (kc * 4 + qd) * 8]);
                accS[nj] = __builtin_amdgcn_mfma_f32_16x16x32_bf16(kf, qf[kc], accS[nj], 0, 0, 0);
            }

        float mx = accS[0][0];
#pragma unroll
        for (int nj = 0; nj < 8; ++nj)
#pragma unroll
            for (int r = 0; r < 4; ++r) mx = fmaxf(mx, accS[nj][r]);
        mx *= C2;
        mx = fmaxf(mx, __shfl_xor(mx, 16));
        mx = fmaxf(mx, __shfl_xor(mx, 32));
        float mn = fmaxf(mrow, mx);
        float alpha = __builtin_amdgcn_exp2f(mrow - mn);
        mrow = mn;
        float ls = 0.f;
        s16x4 pk[8];
#pragma unroll
        for (int nj = 0; nj < 8; ++nj) {
            float p0 = __builtin_amdgcn_exp2f(fmaf(accS[nj][0], C2, -mn));
            float p1 = __builtin_amdgcn_exp2f(fmaf(accS[nj][1], C2, -mn));
            float p2 = __builtin_amdgcn_exp2f(fmaf(accS[nj][2], C2, -mn));
            float p3 = __builtin_amdgcn_exp2f(fmaf(accS[nj][3], C2, -mn));
            ls += (p0 + p1) + (p2 + p3);
            u32 lo = pack_bf16_rhu(p0, p1);
            u32 hi = pack_bf16_rhu(p2, p3);
            uint2 pr = make_uint2(lo, hi);
            pk[nj] = __builtin_bit_cast(s16x4, pr);
        }
        ls += __shfl_xor(ls, 16);
        ls += __shfl_xor(ls, 32);
        lrow = lrow * alpha + ls;
        float aO[4];
#pragma unroll
        for (int r = 0; r < 4; ++r) aO[r] = __shfl(alpha, qd * 4 + r);
#pragma unroll
        for (int dj = 0; dj < 8; ++dj)
#pragma unroll
            for (int r = 0; r < 4; ++r) accO[dj][r] *= aO[r];

#pragma unroll
        for (int kb = 0; kb < 4; ++kb) {
            s16x8 af = __builtin_shufflevector(pk[2 * kb], pk[2 * kb + 1],
                                               0, 1, 2, 3, 4, 5, 6, 7);
#pragma unroll
            for (int dj = 0; dj < 8; ++dj) {
                s16x8 vf = *reinterpret_cast<const s16x8*>(
                    &VS[(dj * 16 + m16) * 136 + kb * 32 + qd * 8]);
                accO[dj] = __builtin_amdgcn_mfma_f32_16x16x32_bf16(af, vf, accO[dj], 0, 0, 0);
            }
        }
    }
    float invl = 1.0f / lrow;
    float iv[4];
#pragma unroll
    for (int r = 0; r < 4; ++r) iv[r] = __shfl(invl, qd * 4 + r);
#pragma unroll
    for (int r = 0; r < 4; ++r) {
        size_t row = (size_t)b * 2048 + q0 + wave * 16 + qd * 4 + r;
#pragma unroll
        for (int dj = 0; dj < 8; ++dj)
            out[row * 2048 + h * 128 + dj * 16 + m16] =
                f32_to_bf16_rne(accO[dj][r] * iv[r]);
    }
}

// ---------- launch: 4 dispatches ----------
extern "C" void kernel_launch(void* const* d_in, const int* in_sizes, int n_in,
                              void* d_out, int out_size, void* d_ws, size_t ws_size,
                              hipStream_t stream) {
    const float* x     = (const float*)d_in[0];
    const float* W_qkv = (const float*)d_in[1];
    const float* W_out = (const float*)d_in[2];
    float* out = (float*)d_out;

    char* ws = (char*)d_ws;
    u16* xb   = (u16*)(ws);
    u16* Wqt  = (u16*)(ws + (16u << 20));
    u16* Wot  = (u16*)(ws + (40u << 20));
    u16* qkvb = (u16*)(ws + (48u << 20));
    u16* attn = (u16*)(ws + (96u << 20));
    u16* vtg  = (u16*)(ws + (112u << 20));

    k_prep<<<6144, 256, 0, stream>>>(x, W_qkv, W_out, xb, Wqt, Wot);
    k_gemm384<<<dim3(16, 32), 512, 0, stream>>>(xb, Wqt, qkvb, vtg, 4096, 6144, 2048);
    k_flash<<<dim3(16, 32), 512, 0, stream>>>(qkvb, vtg, attn);
    k_gemmo<<<dim3(8, 32), 512, 0, stream>>>(attn, Wot, out, 4096, 2048, 2048);
}